// Round 6
// baseline (255.078 us; speedup 1.0000x reference)
//
#include <hip/hip_runtime.h>

#define D 4096
#define R 4   // rows per wave: grid = 8192/4 = 2048 -> 8 blocks/CU, all resident

// In-register 64-point Walsh-Hadamard, butterfly bits in INCREASING order
// (s=1..32) — matches the reference's stage order bitwise (round 5: absmax 0.0).
__device__ __forceinline__ void fwht64(float v[64]) {
#pragma unroll
    for (int s = 1; s < 64; s <<= 1) {
#pragma unroll
        for (int i = 0; i < 64; i++) {
            if (!(i & s)) {
                float a = v[i], b = v[i ^ s];
                v[i]     = a + b;
                v[i ^ s] = a - b;
            }
        }
    }
}

// One WAVE per 4 rows, zero barriers, 2-deep software pipeline in registers.
// Round-5 failure mode: VGPR_Count=68 -> ~2 loads in flight -> latency-bound at
// 92 us. Fix: __launch_bounds__(64,2) (cap 256 VGPR) + explicit u[64] prefetch
// buffer so all 16 next-row dwordx4 loads stay in flight under ~3000 cyc of
// fwht/LDS/store work. No barrier in the kernel ever waits on vmcnt.
//
// LDS transpose layout (per element e, e[11:6]=phase-1 lane, e[5:0]=phase-1 reg):
//   f(e) = 64*e[11:6] + 4*(e[5:2] ^ e[9:6]) + e[1:0]
// Write instr k (lane l): f = 64l + 4*(k^(l&15)) + {0..3} -> ds_write_b128,
//   16B aligned, banks uniformly 8-per-bank (= conflict-free optimum for b128).
// Read instr n (lane l): f = 64n + 4*((l>>2)^(n&15)) + (l&3) -> ds_read_b32,
//   exact 2-way bank aliasing (free).
__global__ __launch_bounds__(64, 2) void fwht_kernel(const float* __restrict__ x,
                                                     const float* __restrict__ signs,
                                                     float* __restrict__ out) {
    __shared__ float lds[4096];  // exactly 16 KB -> 10 blocks/CU by LDS

    const int l = threadIdx.x;   // 0..63
    const long row0 = (long)blockIdx.x * R;

    float s[64], u[64], v[64];

    // ---- signs into registers, once per wave: s[r] = signs[64l + r] ----
    {
        const float4* __restrict__ sv = (const float4*)(signs + l * 64);
#pragma unroll
        for (int k = 0; k < 16; k++) {
            float4 g = sv[k];
            s[4 * k + 0] = g.x; s[4 * k + 1] = g.y;
            s[4 * k + 2] = g.z; s[4 * k + 3] = g.w;
        }
    }
    // ---- prologue prefetch: row0 -> u ----
    {
        const float4* __restrict__ xv = (const float4*)(x + row0 * (long)D + l * 64);
#pragma unroll
        for (int k = 0; k < 16; k++) {
            float4 a = xv[k];
            u[4 * k + 0] = a.x; u[4 * k + 1] = a.y;
            u[4 * k + 2] = a.z; u[4 * k + 3] = a.w;
        }
    }

#pragma unroll
    for (int i = 0; i < R; i++) {
        // Consume prefetch (compiler emits the vmcnt wait here), freeing u.
#pragma unroll
        for (int r = 0; r < 64; r++) v[r] = u[r] * s[r];

        // Issue next row's 16 loads immediately; they complete under the
        // ~3000 cyc of compute below. Nothing below waits on vmcnt.
        if (i + 1 < R) {
            const float4* __restrict__ xv =
                (const float4*)(x + (row0 + i + 1) * (long)D + l * 64);
#pragma unroll
            for (int k = 0; k < 16; k++) {
                float4 a = xv[k];
                u[4 * k + 0] = a.x; u[4 * k + 1] = a.y;
                u[4 * k + 2] = a.z; u[4 * k + 3] = a.w;
            }
        }

        fwht64(v);  // butterfly bits 0..5 (reference order)

        // ---- XOR-swizzled transpose: 16x ds_write_b128, then 64x ds_read_b32 ----
#pragma unroll
        for (int k = 0; k < 16; k++) {
            float4 w = make_float4(v[4 * k + 0], v[4 * k + 1],
                                   v[4 * k + 2], v[4 * k + 3]);
            *(float4*)&lds[64 * l + 4 * (k ^ (l & 15))] = w;
        }
        // Same-wave write->read ordering; fence + sched_barrier (guide rule #18).
        asm volatile("s_waitcnt lgkmcnt(0)" ::: "memory");
        __builtin_amdgcn_sched_barrier(0);
#pragma unroll
        for (int n = 0; n < 64; n++)
            v[n] = lds[64 * n + 4 * ((l >> 2) ^ (n & 15)) + (l & 3)];

        fwht64(v);  // butterfly bits 6..11 (reference order)

        // ---- store: out[row*D + 64n + l], 256 B contiguous per instruction ----
        const float scale = 1.0f / 64.0f;  // 4096^-0.5
        float* __restrict__ orow = out + (row0 + i) * (long)D + l;
#pragma unroll
        for (int n = 0; n < 64; n++) orow[64 * n] = v[n] * scale;
        // Row i's LDS reads were all consumed by fwht64 above (lgkmcnt-drained
        // before use), so row i+1's writes cannot race them.
    }
}

extern "C" void kernel_launch(void* const* d_in, const int* in_sizes, int n_in,
                              void* d_out, int out_size, void* d_ws, size_t ws_size,
                              hipStream_t stream) {
    const float* x = (const float*)d_in[0];
    const float* signs = (const float*)d_in[1];
    float* out = (float*)d_out;
    const int rows = in_sizes[0] / D;  // 8192
    fwht_kernel<<<dim3(rows / R), dim3(64), 0, stream>>>(x, signs, out);
}

// Round 7
// 231.480 us; speedup vs baseline: 1.1019x; 1.1019x over previous
//
#include <hip/hip_runtime.h>

#define D 4096
#define RPB 2   // rows per block: grid = 4096 -> 2 dispatch generations per CU

// In-register 16-point Walsh-Hadamard (natural order butterflies).
// Global stage order across P1/P2/P3 is h=1..2048 sequential -> op DAG is
// bitwise-identical to the jax reference (round 0/5: absmax 0.0).
__device__ __forceinline__ void fwht16(float v[16]) {
#pragma unroll
    for (int s = 1; s < 16; s <<= 1) {
#pragma unroll
        for (int i = 0; i < 16; i++) {
            if (!(i & s)) {
                float a = v[i], b = v[i ^ s];
                v[i]     = a + b;
                v[i ^ s] = a - b;
            }
        }
    }
}

// Raw barriers that never drain vmcnt -> the cross-row prefetch loads stay in
// flight across them (__syncthreads would force s_waitcnt vmcnt(0)).
// lgkm_barrier: each wave's own ds_writes drained (lgkmcnt(0)) before arrival,
// so after the barrier all waves' writes are visible. Compiler fences stop
// hipcc hoisting the next phase's DS ops above the barrier (round-1 race fix).
__device__ __forceinline__ void lgkm_barrier() {
    asm volatile("s_waitcnt lgkmcnt(0)" ::: "memory");
    __builtin_amdgcn_s_barrier();
    asm volatile("" ::: "memory");
}
// plain_barrier (end of row): every wave's P3 ds_reads were hardware-complete
// before it could consume them in fwht16, so arrival at the barrier implies
// its reads are done; next row's P1 writes after the barrier cannot race.
__device__ __forceinline__ void plain_barrier() {
    asm volatile("" ::: "memory");
    __builtin_amdgcn_s_barrier();
    asm volatile("" ::: "memory");
}

// Round-0 structure (best measured: ~68.6 us kernel, 32 waves/CU) + 2-row
// register pipeline. Per-thread arrays v[16]+u[16] ~= 56-60 VGPR < 64 so the
// full 8 waves/SIMD occupancy is preserved and nothing can spill (round 6's
// failure). Signs (16 KB) are re-loaded each row and stay L1-resident.
//
// LDS layout (round 0, measured 0 bank conflicts): element i = 16T + b lives
// at f = 17T + b = 272*a2 + 17*a1 + b where T = (a2<<4)|a1.
__global__ __launch_bounds__(256) void fwht_kernel(const float* __restrict__ x,
                                                   const float* __restrict__ signs,
                                                   float* __restrict__ out) {
    __shared__ float lds[4352];  // 4096 + 256 pad floats = 17 KB

    const int t = threadIdx.x;
    const long row0 = (long)blockIdx.x * RPB;

    float v[16], u[16];

    // ---- prologue: prefetch row0 (4x dwordx4, 16 B/lane coalesced) ----
    {
        const float4* __restrict__ xv = (const float4*)(x + row0 * (long)D + t * 16);
#pragma unroll
        for (int k = 0; k < 4; k++) {
            float4 a = xv[k];
            u[4 * k + 0] = a.x; u[4 * k + 1] = a.y;
            u[4 * k + 2] = a.z; u[4 * k + 3] = a.w;
        }
    }

    const int base2 = (t >> 4) * 272 + (t & 15);  // P2: f = base2 + a1*17
    const int base3 = (t >> 4) * 17 + (t & 15);   // P3: f = base3 + a2*272

#pragma unroll
    for (int i = 0; i < RPB; i++) {
        // ---- consume prefetch; signs re-loaded (L1-resident after row 0) ----
        {
            const float4* __restrict__ sv = (const float4*)(signs + t * 16);
#pragma unroll
            for (int k = 0; k < 4; k++) {
                float4 s = sv[k];
                v[4 * k + 0] = u[4 * k + 0] * s.x;
                v[4 * k + 1] = u[4 * k + 1] * s.y;
                v[4 * k + 2] = u[4 * k + 2] * s.z;
                v[4 * k + 3] = u[4 * k + 3] * s.w;
            }
        }

        // ---- issue next row's prefetch NOW; nothing below waits on vmcnt,
        //      so these 4 loads hide under ~2000 cyc of DS+VALU work ----
        if (i + 1 < RPB) {
            const float4* __restrict__ xv =
                (const float4*)(x + (row0 + i + 1) * (long)D + t * 16);
#pragma unroll
            for (int k = 0; k < 4; k++) {
                float4 a = xv[k];
                u[4 * k + 0] = a.x; u[4 * k + 1] = a.y;
                u[4 * k + 2] = a.z; u[4 * k + 3] = a.w;
            }
        }

        // ---- P1: H16 over bits 0-3; contiguous padded write (4x ds_write_b128)
        fwht16(v);
#pragma unroll
        for (int q = 0; q < 16; q++) lds[17 * t + q] = v[q];
        lgkm_barrier();

        // ---- P2: gather stride 17 over a1 (bits 4-7), write back in place ----
#pragma unroll
        for (int a1 = 0; a1 < 16; a1++) v[a1] = lds[base2 + a1 * 17];
        fwht16(v);
#pragma unroll
        for (int a1 = 0; a1 < 16; a1++) lds[base2 + a1 * 17] = v[a1];
        lgkm_barrier();

        // ---- P3: gather stride 272 over a2 (bits 8-11), coalesced store ----
#pragma unroll
        for (int a2 = 0; a2 < 16; a2++) v[a2] = lds[base3 + a2 * 272];
        fwht16(v);
        {
            const float scale = 1.0f / 64.0f;  // 4096^-0.5
            float* __restrict__ orow = out + (row0 + i) * (long)D;
            // element = a2*256 + t: each instr = 256 B contiguous wave write
#pragma unroll
            for (int a2 = 0; a2 < 16; a2++) orow[a2 * 256 + t] = v[a2] * scale;
        }

        if (i + 1 < RPB) plain_barrier();
    }
}

extern "C" void kernel_launch(void* const* d_in, const int* in_sizes, int n_in,
                              void* d_out, int out_size, void* d_ws, size_t ws_size,
                              hipStream_t stream) {
    const float* x = (const float*)d_in[0];
    const float* signs = (const float*)d_in[1];
    float* out = (float*)d_out;
    const int rows = in_sizes[0] / D;  // 8192
    fwht_kernel<<<dim3(rows / RPB), dim3(256), 0, stream>>>(x, signs, out);
}